// Round 1
// baseline (1540.411 us; speedup 1.0000x reference)
//
#include <hip/hip_runtime.h>
#include <stdint.h>
#include <stddef.h>

#define DIM_C    384
#define NHEADS   12
#define SEQ      49
#define HEADD    32
#define NWIN     4096
#define MTOT     (NWIN * SEQ)     // 200704
#define QKV_N    (3 * DIM_C)      // 1152
#define ATTN_SCALE 0.17677669529663687f

typedef __bf16 bf16_t;
typedef __bf16 bf16x8 __attribute__((ext_vector_type(8)));
typedef __bf16 bf16x4 __attribute__((ext_vector_type(4)));
typedef float  f32x4  __attribute__((ext_vector_type(4)));

static_assert(sizeof(bf16x8) == 16, "bf16x8 must be 16B");

#define QKV_BYTES   ((size_t)MTOT * QKV_N * 2)   // 462,422,016
#define AOUT_BYTES  ((size_t)MTOT * DIM_C * 2)   // 154,140,672
#define BIAS_ELEMS  (NHEADS * SEQ * SEQ)         // 28,812

// ---------------------------------------------------------------------------
// Kernel 1: expand bias_table[rel_index] -> bias_full[h][m][n] (f32)
// ---------------------------------------------------------------------------
__global__ void bias_expand_kernel(const float* __restrict__ table,
                                   const int* __restrict__ rel,
                                   float* __restrict__ bias_full) {
    int i = blockIdx.x * 256 + threadIdx.x;
    if (i < BIAS_ELEMS) {
        int h  = i / (SEQ * SEQ);
        int mn = i % (SEQ * SEQ);
        bias_full[i] = table[rel[mn] * NHEADS + h];
    }
}

// ---------------------------------------------------------------------------
// Kernel 2/4: 128x128 tile MFMA GEMM, K=384, C[m,n] = sum_k A[m,k]*B[n,k]+bias[n]
// A: f32 (converted during staging) or bf16. B: f32 weights [N,384].
// ---------------------------------------------------------------------------
template <bool A_BF16, bool OUT_BF16>
__global__ __launch_bounds__(256) void gemm_kernel(
    const void* __restrict__ Av, const float* __restrict__ B,
    const float* __restrict__ bias, void* __restrict__ Cv, int ldc) {
    // LDS tiles, padded row stride 40 elems (80 B) -> 16B-aligned b128 frag reads,
    // max 2-way bank aliasing (free per m136).
    __shared__ bf16_t As[128 * 40];
    __shared__ bf16_t Bs[128 * 40];

    const int tid  = threadIdx.x;
    const int lane = tid & 63;
    const int wave = tid >> 6;
    const int l15  = lane & 15;
    const int quad = lane >> 4;
    const int wm = (wave >> 1) * 64;   // wave row offset in tile
    const int wn = (wave & 1) * 64;    // wave col offset in tile
    const size_t m0 = (size_t)blockIdx.y * 128;
    const int    n0 = blockIdx.x * 128;

    f32x4 acc[4][4];
#pragma unroll
    for (int i = 0; i < 4; i++)
#pragma unroll
        for (int j = 0; j < 4; j++) acc[i][j] = f32x4{0.f, 0.f, 0.f, 0.f};

    for (int kt = 0; kt < DIM_C / 32; ++kt) {
        const int k0 = kt * 32;
        __syncthreads();
        // ---- stage A tile: 128 rows x 32 k ----
        if constexpr (A_BF16) {
            const bf16_t* A = (const bf16_t*)Av;
#pragma unroll
            for (int i = 0; i < 2; i++) {
                int c = tid + i * 256;        // 512 chunks of 8 bf16
                int row = c >> 2, kq = c & 3;
                bf16x8 v = *(const bf16x8*)(A + (m0 + row) * DIM_C + k0 + kq * 8);
                *(bf16x8*)(&As[row * 40 + kq * 8]) = v;
            }
        } else {
            const float* A = (const float*)Av;
#pragma unroll
            for (int i = 0; i < 4; i++) {
                int c = tid + i * 256;        // 1024 chunks of 4 f32
                int row = c >> 3, kq = c & 7;
                float4 v = *(const float4*)(A + (m0 + row) * DIM_C + k0 + kq * 4);
                bf16x4 t;
                t[0] = (bf16_t)v.x; t[1] = (bf16_t)v.y;
                t[2] = (bf16_t)v.z; t[3] = (bf16_t)v.w;
                *(bf16x4*)(&As[row * 40 + kq * 4]) = t;
            }
        }
        // ---- stage B tile (always f32 weights) ----
        {
#pragma unroll
            for (int i = 0; i < 4; i++) {
                int c = tid + i * 256;
                int row = c >> 3, kq = c & 7;
                float4 v = *(const float4*)(B + (size_t)(n0 + row) * DIM_C + k0 + kq * 4);
                bf16x4 t;
                t[0] = (bf16_t)v.x; t[1] = (bf16_t)v.y;
                t[2] = (bf16_t)v.z; t[3] = (bf16_t)v.w;
                *(bf16x4*)(&Bs[row * 40 + kq * 4]) = t;
            }
        }
        __syncthreads();
        // ---- fragments + MFMA ----
        bf16x8 af[4], bfr[4];
#pragma unroll
        for (int mi = 0; mi < 4; mi++)
            af[mi] = *(const bf16x8*)(&As[(wm + mi * 16 + l15) * 40 + quad * 8]);
#pragma unroll
        for (int ni = 0; ni < 4; ni++)
            bfr[ni] = *(const bf16x8*)(&Bs[(wn + ni * 16 + l15) * 40 + quad * 8]);
#pragma unroll
        for (int mi = 0; mi < 4; mi++)
#pragma unroll
            for (int ni = 0; ni < 4; ni++)
                acc[mi][ni] = __builtin_amdgcn_mfma_f32_16x16x32_bf16(
                    af[mi], bfr[ni], acc[mi][ni], 0, 0, 0);
    }
    // ---- epilogue: C/D layout col=lane&15, row=quad*4+reg ----
#pragma unroll
    for (int mi = 0; mi < 4; mi++) {
#pragma unroll
        for (int ni = 0; ni < 4; ni++) {
            int col = n0 + wn + ni * 16 + l15;
            float bc = bias[col];
#pragma unroll
            for (int r = 0; r < 4; r++) {
                size_t row = m0 + wm + mi * 16 + quad * 4 + r;
                float v = acc[mi][ni][r] + bc;
                if constexpr (OUT_BF16)
                    ((bf16_t*)Cv)[row * (size_t)ldc + col] = (bf16_t)v;
                else
                    ((float*)Cv)[row * (size_t)ldc + col] = v;
            }
        }
    }
}

// ---------------------------------------------------------------------------
// Kernel 3: fused window attention. 1 block / window, 1 wave handles 3 heads.
// qkv row-major [MTOT, 1152]; q cols h*32, k cols 384+h*32, v cols 768+h*32.
// ---------------------------------------------------------------------------
__global__ __launch_bounds__(256) void attn_kernel(
    const bf16_t* __restrict__ qkv, const float* __restrict__ bias_full,
    bf16_t* __restrict__ aout) {
    // per-wave P scratch: 64 rows x stride 72 elems (144 B: 16B-aligned b128 reads)
    __shared__ bf16_t Ps[4][64 * 72];

    const int b    = blockIdx.x;
    const int lane = threadIdx.x & 63;
    const int wave = threadIdx.x >> 6;
    const int l15  = lane & 15;
    const int quad = lane >> 4;
    const bf16_t* base = qkv + (size_t)b * SEQ * QKV_N;
    bf16_t* ps = &Ps[wave][0];

#pragma unroll 1
    for (int hi = 0; hi < 3; ++hi) {
        const int h = wave * 3 + hi;
        // ---- Q/K fragments straight from global (A/B frag = 8 contiguous k) ----
        bf16x8 qf[4], kf[4];
#pragma unroll
        for (int mi = 0; mi < 4; mi++) {
            int row = mi * 16 + l15;
            if (row < SEQ) {
                qf[mi] = *(const bf16x8*)(base + (size_t)row * QKV_N + h * HEADD + quad * 8);
                kf[mi] = *(const bf16x8*)(base + (size_t)row * QKV_N + DIM_C + h * HEADD + quad * 8);
            } else {
                bf16x8 z;
#pragma unroll
                for (int j = 0; j < 8; j++) z[j] = (bf16_t)0.f;
                qf[mi] = z; kf[mi] = z;
            }
        }
        // ---- S = Q K^T (64x64 padded) ----
        f32x4 S[4][4];
#pragma unroll
        for (int mi = 0; mi < 4; mi++)
#pragma unroll
            for (int ni = 0; ni < 4; ni++)
                S[mi][ni] = __builtin_amdgcn_mfma_f32_16x16x32_bf16(
                    qf[mi], kf[ni], f32x4{0.f, 0.f, 0.f, 0.f}, 0, 0, 0);
        // ---- scale + bias + mask (C layout: m = mi*16+quad*4+r, n = ni*16+l15) ----
        const float* bh = bias_full + h * SEQ * SEQ;
#pragma unroll
        for (int mi = 0; mi < 4; mi++)
#pragma unroll
            for (int r = 0; r < 4; r++) {
                int m = mi * 16 + quad * 4 + r;
#pragma unroll
                for (int ni = 0; ni < 4; ni++) {
                    int n = ni * 16 + l15;
                    float s = S[mi][ni][r];
                    s = (m < SEQ && n < SEQ) ? s * ATTN_SCALE + bh[m * SEQ + n] : -1e30f;
                    S[mi][ni][r] = s;
                }
            }
        // ---- row softmax: reduce across the 16 lanes of each quad-group ----
#pragma unroll
        for (int mi = 0; mi < 4; mi++)
#pragma unroll
            for (int r = 0; r < 4; r++) {
                float mx = -1e30f;
#pragma unroll
                for (int ni = 0; ni < 4; ni++) mx = fmaxf(mx, S[mi][ni][r]);
#pragma unroll
                for (int off = 1; off < 16; off <<= 1)
                    mx = fmaxf(mx, __shfl_xor(mx, off, 64));
                float sum = 0.f;
#pragma unroll
                for (int ni = 0; ni < 4; ni++) {
                    float e = __expf(S[mi][ni][r] - mx);
                    S[mi][ni][r] = e;
                    sum += e;
                }
#pragma unroll
                for (int off = 1; off < 16; off <<= 1)
                    sum += __shfl_xor(sum, off, 64);
                float inv = 1.f / sum;
                int m = mi * 16 + quad * 4 + r;
#pragma unroll
                for (int ni = 0; ni < 4; ni++) {
                    int n = ni * 16 + l15;
                    ps[m * 72 + n] = (bf16_t)(S[mi][ni][r] * inv);
                }
            }
        // ---- V fragments: B[k][d], k strided rows (guarded), d contiguous lanes ----
        bf16x8 vf[2][2];
#pragma unroll
        for (int ki = 0; ki < 2; ki++)
#pragma unroll
            for (int di = 0; di < 2; di++) {
#pragma unroll
                for (int j = 0; j < 8; j++) {
                    int k = ki * 32 + quad * 8 + j;
                    vf[ki][di][j] = (k < SEQ)
                        ? base[(size_t)k * QKV_N + 2 * DIM_C + h * HEADD + di * 16 + l15]
                        : (bf16_t)0.f;
                }
            }
        // ---- O = P V  (P A-frags from LDS) ----
        f32x4 O[4][2];
#pragma unroll
        for (int mi = 0; mi < 4; mi++)
#pragma unroll
            for (int di = 0; di < 2; di++) O[mi][di] = f32x4{0.f, 0.f, 0.f, 0.f};
#pragma unroll
        for (int mi = 0; mi < 4; mi++)
#pragma unroll
            for (int ki = 0; ki < 2; ki++) {
                bf16x8 pa = *(const bf16x8*)(ps + (mi * 16 + l15) * 72 + ki * 32 + quad * 8);
#pragma unroll
                for (int di = 0; di < 2; di++)
                    O[mi][di] = __builtin_amdgcn_mfma_f32_16x16x32_bf16(
                        pa, vf[ki][di], O[mi][di], 0, 0, 0);
            }
        // ---- store O rows m<49, layout [b*49+m, h*32+d] ----
#pragma unroll
        for (int mi = 0; mi < 4; mi++)
#pragma unroll
            for (int di = 0; di < 2; di++)
#pragma unroll
                for (int r = 0; r < 4; r++) {
                    int m = mi * 16 + quad * 4 + r;
                    if (m < SEQ)
                        aout[((size_t)b * SEQ + m) * DIM_C + h * HEADD + di * 16 + l15] =
                            (bf16_t)O[mi][di][r];
                }
    }
}

// ---------------------------------------------------------------------------
extern "C" void kernel_launch(void* const* d_in, const int* in_sizes, int n_in,
                              void* d_out, int out_size, void* d_ws, size_t ws_size,
                              hipStream_t stream) {
    (void)in_sizes; (void)n_in; (void)out_size; (void)ws_size;
    const float* x      = (const float*)d_in[0];
    const float* qkv_w  = (const float*)d_in[1];
    const float* qkv_b  = (const float*)d_in[2];
    const float* proj_w = (const float*)d_in[3];
    const float* proj_b = (const float*)d_in[4];
    const float* btable = (const float*)d_in[5];
    const int*   rel    = (const int*)d_in[6];
    float* out = (float*)d_out;

    char* ws = (char*)d_ws;
    bf16_t* qkv       = (bf16_t*)ws;
    bf16_t* aout      = (bf16_t*)(ws + QKV_BYTES);
    float*  bias_full = (float*)(ws + QKV_BYTES + AOUT_BYTES);

    bias_expand_kernel<<<(BIAS_ELEMS + 255) / 256, 256, 0, stream>>>(btable, rel, bias_full);
    gemm_kernel<false, true><<<dim3(QKV_N / 128, MTOT / 128), 256, 0, stream>>>(
        x, qkv_w, qkv_b, qkv, QKV_N);
    attn_kernel<<<NWIN, 256, 0, stream>>>(qkv, bias_full, aout);
    gemm_kernel<true, false><<<dim3(DIM_C / 128, MTOT / 128), 256, 0, stream>>>(
        aout, proj_w, proj_b, out, DIM_C);
}